// Round 1
// baseline (410.946 us; speedup 1.0000x reference)
//
#include <hip/hip_runtime.h>
#include <cmath>

// Shapes: B=4, V=8, D=64, N=16, H=32, W=32, GROUPS=4
// rotation tables: a = radians(-45*v); c = cos(a), s = sin(a)
#define FSQ 0.70710678118654752440f
__constant__ float CTAB[8] = {1.f,  FSQ, 0.f, -FSQ, -1.f, -FSQ, 0.f, FSQ};
__constant__ float STAB[8] = {0.f, -FSQ, -1.f, -FSQ,  0.f,  FSQ, 1.f, FSQ};

// ---------------------------------------------------------------------------
// GroupNorm: 16 blocks = (b, group), 1024 threads (4x the memory parallelism
// of the 256-thread version on the 16 busy CUs). Wave-shuffle reduction.
// Writes u_norm into zero-padded (34x34) planes in ws.
// ---------------------------------------------------------------------------
__global__ __launch_bounds__(1024) void gn_kernel(const float* __restrict__ u,
                                                  const float* __restrict__ gw,
                                                  const float* __restrict__ gb,
                                                  float* __restrict__ up)
{
    int blk = blockIdx.x;            // b*4 + g
    int b = blk >> 2, g = blk & 3;
    int t = threadIdx.x;
    const float* src = u + ((size_t)(b * 64 + g * 16) << 10);   // 16384 floats
    float sum = 0.f, sq = 0.f;
    #pragma unroll
    for (int r = 0; r < 16; ++r) {
        float v = src[t + (r << 10)];
        sum += v; sq += v * v;
    }
    // wave-level reduce (64 lanes)
    #pragma unroll
    for (int ofs = 32; ofs > 0; ofs >>= 1) {
        sum += __shfl_down(sum, ofs);
        sq  += __shfl_down(sq, ofs);
    }
    __shared__ float red[16], red2[16];
    int wv = t >> 6;
    if ((t & 63) == 0) { red[wv] = sum; red2[wv] = sq; }
    __syncthreads();
    float s_tot = 0.f, q_tot = 0.f;
    #pragma unroll
    for (int k = 0; k < 16; ++k) { s_tot += red[k]; q_tot += red2[k]; }
    float mu  = s_tot * (1.f / 16384.f);
    float var = q_tot * (1.f / 16384.f) - mu * mu;
    float rs  = rsqrtf(var + 1e-5f);

    float* pb = up + (size_t)(b * 64 + g * 16) * 1156;
    // zero the 132 border cells of each of my 16 padded planes
    for (int k = t; k < 16 * 132; k += 1024) {
        int pl = k / 132, c = k - pl * 132;
        int idx;
        if (c < 34)       idx = c;                       // row 0
        else if (c < 68)  idx = 33 * 34 + (c - 34);      // row 33
        else if (c < 100) idx = (c - 68 + 1) * 34;       // col 0, rows 1..32
        else              idx = (c - 100 + 1) * 34 + 33; // col 33, rows 1..32
        pb[pl * 1156 + idx] = 0.f;
    }
    // normalized data cells: idx = r*1024 + t -> ch = r, pixel = t
    int y = t >> 5, x = t & 31;
    #pragma unroll
    for (int r = 0; r < 16; ++r) {
        float val = (src[t + (r << 10)] - mu) * rs * gw[g * 16 + r] + gb[g * 16 + r];
        pb[r * 1156 + (y + 1) * 34 + (x + 1)] = val;
    }
}

// ---------------------------------------------------------------------------
// 3x3 SAME convs, LDS-staged, 4 OUTPUT CHANNELS PER BLOCK: 768 blocks =
// (b, ogroup, strip). Each block stages the 6-row x 34-col x 64-ci input
// strip (52 KB) into LDS once, then each LDS tap read is FMA'd into 4
// accumulators (one per output channel) -> 4x fewer ds_reads + 4x fewer
// stagings than one-o-per-block. ogroups align with weight arrays:
// og 0..15 -> conv_delta, 16..19 -> conv_B, 20..23 -> conv_C.
// ---------------------------------------------------------------------------
__global__ __launch_bounds__(256) void conv_kernel(const float* __restrict__ up,
                                                   const float* __restrict__ wd,
                                                   const float* __restrict__ bd,
                                                   const float* __restrict__ wB,
                                                   const float* __restrict__ wC,
                                                   const float* __restrict__ dtb,
                                                   float* __restrict__ delta,
                                                   float* __restrict__ Bv,
                                                   float* __restrict__ Cv)
{
    __shared__ float sin_[64 * 204];   // 64 ci x 6 rows x 34 cols = 52224 B
    int blk = blockIdx.x;              // b*192 + og*8 + strip
    int strip = blk & 7;
    int og = (blk >> 3) % 24;
    int b = blk / 192;
    int h0 = strip * 4;                // output rows h0..h0+3; padded rows h0..h0+5
    int t = threadIdx.x;

    const float* plane = up + (size_t)b * 73984;   // 64*1156
    for (int idx = t; idx < 13056; idx += 256) {   // 13056 = 64*204 = 256*51
        int ci = idx / 204;
        int rem = idx - ci * 204;
        sin_[idx] = plane[ci * 1156 + h0 * 34 + rem];
    }
    __syncthreads();

    int o0 = og * 4;
    const float* wsel;
    if (o0 < 64)      wsel = wd + (size_t)o0 * 576;
    else if (o0 < 80) wsel = wB + (size_t)(o0 - 64) * 576;
    else              wsel = wC + (size_t)(o0 - 80) * 576;

    int half = t >> 7;                 // ci-half (wave-uniform)
    int px = t & 127;
    int r = px >> 5, c = px & 31;      // output row-in-strip, col
    const float* base = sin_ + r * 34 + c;

    float acc0 = 0.f, acc1 = 0.f, acc2 = 0.f, acc3 = 0.f;
    int ci0 = half * 32;
    for (int ci = ci0; ci < ci0 + 32; ++ci) {
        const float* pp = base + ci * 204;
        const float* wp = wsel + ci * 9;
        #pragma unroll
        for (int dy = 0; dy < 3; ++dy)
            #pragma unroll
            for (int dx = 0; dx < 3; ++dx) {
                float v = pp[dy * 34 + dx];
                int wi = dy * 3 + dx;
                acc0 += v * wp[wi];
                acc1 += v * wp[576 + wi];
                acc2 += v * wp[1152 + wi];
                acc3 += v * wp[1728 + wi];
            }
    }
    __syncthreads();                   // sin_ reuse as reduction scratch
    float4* red4 = (float4*)sin_;
    red4[t] = make_float4(acc0, acc1, acc2, acc3);
    __syncthreads();
    if (t < 128) {
        float4 a = red4[t], bq = red4[t + 128];
        float s0 = a.x + bq.x, s1 = a.y + bq.y, s2 = a.z + bq.z, s3 = a.w + bq.w;
        float s[4] = {s0, s1, s2, s3};
        int pidx = (h0 + r) * 32 + c;  // for t<128: r,c as computed above
        if (o0 < 64) {
            #pragma unroll
            for (int k = 0; k < 4; ++k) {
                float x = s[k] + bd[o0 + k] + dtb[0];
                float sp = (x > 20.f) ? x : log1pf(expf(x));
                sp = fminf(fmaxf(sp, 1e-4f), 5.f);
                delta[((size_t)(b * 64 + o0 + k) << 10) + pidx] = sp;
            }
        } else if (o0 < 80) {
            #pragma unroll
            for (int k = 0; k < 4; ++k)
                Bv[((size_t)(b * 16 + o0 - 64 + k) << 10) + pidx] = s[k];
        } else {
            #pragma unroll
            for (int k = 0; k < 4; ++k)
                Cv[((size_t)(b * 16 + o0 - 80 + k) << 10) + pidx] = s[k];
        }
    }
}

// ---------------------------------------------------------------------------
// Main fused kernel: 2048 blocks = (b, v, d). BOTH n-chunks processed
// sequentially in one block over the same 34-stride LDS (guard zeroed once,
// staging only touches interior). Chunk 1 is register-prefetched during
// chunk 0's compute (issue-early / write-late). y accumulated across all
// 16 n in registers -> single plain store; no atomics, no memset.
// Plane layout: idx = n*1156 + (y+1)*34 + (x+1); row stride 34 keeps the
// per-lane bank delta nonzero for all 8 rotations.
// ---------------------------------------------------------------------------
__global__ __launch_bounds__(256, 4) void fused_state_kernel(
    const float* __restrict__ s_prev, const float* __restrict__ u_t,
    const float* __restrict__ delta, const float* __restrict__ Bv,
    const float* __restrict__ Cv, const float* __restrict__ logA,
    const float* __restrict__ Dp, float* __restrict__ y_out,
    float* __restrict__ s_out)
{
    __shared__ float lds[8 * 1156];   // 36992 B
    __shared__ float Ash[16];
    int blk = blockIdx.x;             // b*512 + v*64 + d
    int d = blk & 63, v = (blk >> 6) & 7, b = blk >> 9;
    int t = threadIdx.x;

    if (t < 16) Ash[t] = -__expf(logA[d * 16 + t]);
    // zero guard cells once (8 planes x 132); staging never dirties them
    for (int k = t; k < 1056; k += 256) {
        int pl = k / 132, g = k - pl * 132;
        int idx;
        if (g < 34)       idx = g;                  // row 0
        else if (g < 68)  idx = 1122 + (g - 34);    // row 33
        else if (g < 100) idx = (g - 67) * 34;      // col 0, rows 1..32
        else              idx = (g - 99) * 34 + 33; // col 33, rows 1..32
        lds[pl * 1156 + idx] = 0.f;
    }

    size_t so = ((size_t)((b * 8 + v) * 64 + d)) << 14;   // 16384 floats/(b,v,d)
    const float4* src0 = (const float4*)(s_prev + so);
    const float4* src1 = (const float4*)(s_prev + so + 8192);

    float4 rg[8];
    #pragma unroll
    for (int k = 0; k < 8; ++k) rg[k] = src0[t + (k << 8)];
    #pragma unroll
    for (int k = 0; k < 8; ++k) {
        int q = t + (k << 8);
        int lin = q << 2;
        int nn = lin >> 10, rem = lin & 1023;
        int di = nn * 1156 + ((rem >> 5) + 1) * 34 + (rem & 31) + 1;
        lds[di] = rg[k].x; lds[di + 1] = rg[k].y; lds[di + 2] = rg[k].z; lds[di + 3] = rg[k].w;
    }
    __syncthreads();
    // prefetch chunk 1 into registers; completes under chunk-0 compute
    #pragma unroll
    for (int k = 0; k < 8; ++k) rg[k] = src1[t + (k << 8)];

    const float cc = CTAB[v], ss = STAB[v];
    const float* dpl = delta + ((size_t)(b * 64 + d) << 10);
    const float* upl = u_t   + ((size_t)(b * 64 + d) << 10);
    float* soc = s_out + so;
    float* yo  = y_out + (((size_t)((b * 8 + v) * 64 + d)) << 10);
    float Dd = Dp[d];

    // per-pixel invariants (shared by both chunks)
    float dd[4], uv[4], du[4], yacc[4];
    float w00[4], w01[4], w10[4], w11[4];
    int tbase[4];
    #pragma unroll
    for (int i = 0; i < 4; ++i) {
        int p = t + (i << 8);
        int h = p >> 5, wpx = p & 31;
        float X = (wpx + 0.5f) * 0.0625f - 1.f;
        float Y = (h + 0.5f) * 0.0625f - 1.f;
        float gx = cc * X - ss * Y;
        float gy = ss * X + cc * Y;
        float ix = (gx + 1.f) * 16.f - 0.5f;
        float iy = (gy + 1.f) * 16.f - 0.5f;
        float fx0 = floorf(ix), fy0 = floorf(iy);
        float wx = ix - fx0, wy = iy - fy0;
        int x0 = (int)fx0, y0 = (int)fy0;
        float mx0 = (x0 >= 0 && x0 < 32) ? (1.f - wx) : 0.f;
        float mx1 = (x0 >= -1 && x0 < 31) ? wx : 0.f;
        float my0 = (y0 >= 0 && y0 < 32) ? (1.f - wy) : 0.f;
        float my1 = (y0 >= -1 && y0 < 31) ? wy : 0.f;
        w00[i] = my0 * mx0; w01[i] = my0 * mx1;
        w10[i] = my1 * mx0; w11[i] = my1 * mx1;
        int bx = min(max(x0, -1), 31), by = min(max(y0, -1), 31);
        tbase[i] = (by + 1) * 34 + (bx + 1);   // taps +0,+1,+34,+35 (guard zeroed)
        dd[i] = dpl[p]; uv[i] = upl[p]; du[i] = dd[i] * uv[i];
        yacc[i] = 0.f;
    }

    // ---- chunk 0 compute ----
    {
        const float* bvc = Bv + ((size_t)b << 14);
        const float* cvc = Cv + ((size_t)b << 14);
        #pragma unroll
        for (int i = 0; i < 4; ++i) {
            int p = t + (i << 8);
            #pragma unroll
            for (int nn = 0; nn < 8; ++nn) {
                int si = tbase[i] + nn * 1156;
                float s00 = lds[si], s01 = lds[si + 1];
                float s10 = lds[si + 34], s11 = lds[si + 35];
                float bil = s00 * w00[i] + s01 * w01[i] + s10 * w10[i] + s11 * w11[i];
                float abar = __expf(dd[i] * Ash[nn]);
                float sn = abar * bil + du[i] * bvc[(nn << 10) + p];
                soc[(nn << 10) + p] = sn;
                yacc[i] += sn * cvc[(nn << 10) + p];
            }
        }
    }
    __syncthreads();                  // all chunk-0 LDS reads done
    // write prefetched chunk 1 into LDS
    #pragma unroll
    for (int k = 0; k < 8; ++k) {
        int q = t + (k << 8);
        int lin = q << 2;
        int nn = lin >> 10, rem = lin & 1023;
        int di = nn * 1156 + ((rem >> 5) + 1) * 34 + (rem & 31) + 1;
        lds[di] = rg[k].x; lds[di + 1] = rg[k].y; lds[di + 2] = rg[k].z; lds[di + 3] = rg[k].w;
    }
    __syncthreads();
    // ---- chunk 1 compute ----
    {
        const float* bvc = Bv + ((size_t)b << 14) + 8192;
        const float* cvc = Cv + ((size_t)b << 14) + 8192;
        float* soc1 = soc + 8192;
        #pragma unroll
        for (int i = 0; i < 4; ++i) {
            int p = t + (i << 8);
            #pragma unroll
            for (int nn = 0; nn < 8; ++nn) {
                int si = tbase[i] + nn * 1156;
                float s00 = lds[si], s01 = lds[si + 1];
                float s10 = lds[si + 34], s11 = lds[si + 35];
                float bil = s00 * w00[i] + s01 * w01[i] + s10 * w10[i] + s11 * w11[i];
                float abar = __expf(dd[i] * Ash[8 + nn]);
                float sn = abar * bil + du[i] * bvc[(nn << 10) + p];
                soc1[(nn << 10) + p] = sn;
                yacc[i] += sn * cvc[(nn << 10) + p];
            }
        }
    }
    // single plain y store (no atomics, no pre-zero)
    #pragma unroll
    for (int i = 0; i < 4; ++i) {
        int p = t + (i << 8);
        yo[p] = yacc[i] + uv[i] * Dd;
    }
}

// ---------------------------------------------------------------------------
extern "C" void kernel_launch(void* const* d_in, const int* in_sizes, int n_in,
                              void* d_out, int out_size, void* d_ws, size_t ws_size,
                              hipStream_t stream)
{
    const float* u_t    = (const float*)d_in[0];
    const float* s_prev = (const float*)d_in[1];
    const float* gn_w   = (const float*)d_in[2];
    const float* gn_b   = (const float*)d_in[3];
    const float* wd     = (const float*)d_in[4];
    const float* bd     = (const float*)d_in[5];
    const float* wB     = (const float*)d_in[6];
    const float* wC     = (const float*)d_in[7];
    const float* logA   = (const float*)d_in[8];
    const float* Dp     = (const float*)d_in[9];
    const float* dtb    = (const float*)d_in[10];

    float* y_out = (float*)d_out;            // (4,8,64,32,32) = 2097152 floats
    float* s_out = y_out + 2097152;          // (4,8,64,16,32,32) = 33554432 floats

    float* up    = (float*)d_ws;             // padded u_norm: 4*64*1156 = 295936
    float* delta = up + 295936;              // 4*64*1024 = 262144
    float* Bv    = delta + 262144;           // 4*16*1024 = 65536
    float* Cv    = Bv + 65536;               // 65536

    hipLaunchKernelGGL(gn_kernel, dim3(16), dim3(1024), 0, stream, u_t, gn_w, gn_b, up);
    hipLaunchKernelGGL(conv_kernel, dim3(768), dim3(256), 0, stream,
                       up, wd, bd, wB, wC, dtb, delta, Bv, Cv);
    hipLaunchKernelGGL(fused_state_kernel, dim3(2048), dim3(256), 0, stream,
                       s_prev, u_t, delta, Bv, Cv, logA, Dp, y_out, s_out);
}

// Round 2
// 305.280 us; speedup vs baseline: 1.3461x; 1.3461x over previous
//
#include <hip/hip_runtime.h>
#include <cmath>

// Shapes: B=4, V=8, D=64, N=16, H=32, W=32, GROUPS=4
// rotation tables: a = radians(-45*v); c = cos(a), s = sin(a)
#define FSQ 0.70710678118654752440f
__constant__ float CTAB[8] = {1.f,  FSQ, 0.f, -FSQ, -1.f, -FSQ, 0.f, FSQ};
__constant__ float STAB[8] = {0.f, -FSQ, -1.f, -FSQ,  0.f,  FSQ, 1.f, FSQ};

// ---------------------------------------------------------------------------
// GroupNorm: 16 blocks = (b, group), 1024 threads. Wave-shuffle reduction.
// Writes u_norm into zero-padded (34x34) planes in ws.
// ---------------------------------------------------------------------------
__global__ __launch_bounds__(1024) void gn_kernel(const float* __restrict__ u,
                                                  const float* __restrict__ gw,
                                                  const float* __restrict__ gb,
                                                  float* __restrict__ up)
{
    int blk = blockIdx.x;            // b*4 + g
    int b = blk >> 2, g = blk & 3;
    int t = threadIdx.x;
    const float* src = u + ((size_t)(b * 64 + g * 16) << 10);   // 16384 floats
    float sum = 0.f, sq = 0.f;
    #pragma unroll
    for (int r = 0; r < 16; ++r) {
        float v = src[t + (r << 10)];
        sum += v; sq += v * v;
    }
    // wave-level reduce (64 lanes)
    #pragma unroll
    for (int ofs = 32; ofs > 0; ofs >>= 1) {
        sum += __shfl_down(sum, ofs);
        sq  += __shfl_down(sq, ofs);
    }
    __shared__ float red[16], red2[16];
    int wv = t >> 6;
    if ((t & 63) == 0) { red[wv] = sum; red2[wv] = sq; }
    __syncthreads();
    float s_tot = 0.f, q_tot = 0.f;
    #pragma unroll
    for (int k = 0; k < 16; ++k) { s_tot += red[k]; q_tot += red2[k]; }
    float mu  = s_tot * (1.f / 16384.f);
    float var = q_tot * (1.f / 16384.f) - mu * mu;
    float rs  = rsqrtf(var + 1e-5f);

    float* pb = up + (size_t)(b * 64 + g * 16) * 1156;
    // zero the 132 border cells of each of my 16 padded planes
    for (int k = t; k < 16 * 132; k += 1024) {
        int pl = k / 132, c = k - pl * 132;
        int idx;
        if (c < 34)       idx = c;                       // row 0
        else if (c < 68)  idx = 33 * 34 + (c - 34);      // row 33
        else if (c < 100) idx = (c - 68 + 1) * 34;       // col 0, rows 1..32
        else              idx = (c - 100 + 1) * 34 + 33; // col 33, rows 1..32
        pb[pl * 1156 + idx] = 0.f;
    }
    // normalized data cells: idx = r*1024 + t -> ch = r, pixel = t
    int y = t >> 5, x = t & 31;
    #pragma unroll
    for (int r = 0; r < 16; ++r) {
        float val = (src[t + (r << 10)] - mu) * rs * gw[g * 16 + r] + gb[g * 16 + r];
        pb[r * 1156 + (y + 1) * 34 + (x + 1)] = val;
    }
}

// ---------------------------------------------------------------------------
// 3x3 SAME convs, LDS-staged, 4 OUTPUT CHANNELS PER BLOCK: 768 blocks =
// (b, ogroup, strip). Each block stages the 6-row x 34-col x 64-ci input
// strip (52 KB) into LDS once, then each LDS tap read is FMA'd into 4
// accumulators (one per output channel) -> 4x fewer ds_reads + 4x fewer
// stagings than one-o-per-block. ogroups align with weight arrays:
// og 0..15 -> conv_delta, 16..19 -> conv_B, 20..23 -> conv_C.
// ---------------------------------------------------------------------------
__global__ __launch_bounds__(256) void conv_kernel(const float* __restrict__ up,
                                                   const float* __restrict__ wd,
                                                   const float* __restrict__ bd,
                                                   const float* __restrict__ wB,
                                                   const float* __restrict__ wC,
                                                   const float* __restrict__ dtb,
                                                   float* __restrict__ delta,
                                                   float* __restrict__ Bv,
                                                   float* __restrict__ Cv)
{
    __shared__ float sin_[64 * 204];   // 64 ci x 6 rows x 34 cols = 52224 B
    int blk = blockIdx.x;              // b*192 + og*8 + strip
    int strip = blk & 7;
    int og = (blk >> 3) % 24;
    int b = blk / 192;
    int h0 = strip * 4;                // output rows h0..h0+3; padded rows h0..h0+5
    int t = threadIdx.x;

    const float* plane = up + (size_t)b * 73984;   // 64*1156
    for (int idx = t; idx < 13056; idx += 256) {   // 13056 = 64*204 = 256*51
        int ci = idx / 204;
        int rem = idx - ci * 204;
        sin_[idx] = plane[ci * 1156 + h0 * 34 + rem];
    }
    __syncthreads();

    int o0 = og * 4;
    const float* wsel;
    if (o0 < 64)      wsel = wd + (size_t)o0 * 576;
    else if (o0 < 80) wsel = wB + (size_t)(o0 - 64) * 576;
    else              wsel = wC + (size_t)(o0 - 80) * 576;

    int half = t >> 7;                 // ci-half (wave-uniform)
    int px = t & 127;
    int r = px >> 5, c = px & 31;      // output row-in-strip, col
    const float* base = sin_ + r * 34 + c;

    float acc0 = 0.f, acc1 = 0.f, acc2 = 0.f, acc3 = 0.f;
    int ci0 = half * 32;
    for (int ci = ci0; ci < ci0 + 32; ++ci) {
        const float* pp = base + ci * 204;
        const float* wp = wsel + ci * 9;
        #pragma unroll
        for (int dy = 0; dy < 3; ++dy)
            #pragma unroll
            for (int dx = 0; dx < 3; ++dx) {
                float v = pp[dy * 34 + dx];
                int wi = dy * 3 + dx;
                acc0 += v * wp[wi];
                acc1 += v * wp[576 + wi];
                acc2 += v * wp[1152 + wi];
                acc3 += v * wp[1728 + wi];
            }
    }
    __syncthreads();                   // sin_ reuse as reduction scratch
    float4* red4 = (float4*)sin_;
    red4[t] = make_float4(acc0, acc1, acc2, acc3);
    __syncthreads();
    if (t < 128) {
        float4 a = red4[t], bq = red4[t + 128];
        float s0 = a.x + bq.x, s1 = a.y + bq.y, s2 = a.z + bq.z, s3 = a.w + bq.w;
        float s[4] = {s0, s1, s2, s3};
        int pidx = (h0 + r) * 32 + c;  // for t<128: r,c as computed above
        if (o0 < 64) {
            #pragma unroll
            for (int k = 0; k < 4; ++k) {
                float x = s[k] + bd[o0 + k] + dtb[0];
                float sp = (x > 20.f) ? x : log1pf(expf(x));
                sp = fminf(fmaxf(sp, 1e-4f), 5.f);
                delta[((size_t)(b * 64 + o0 + k) << 10) + pidx] = sp;
            }
        } else if (o0 < 80) {
            #pragma unroll
            for (int k = 0; k < 4; ++k)
                Bv[((size_t)(b * 16 + o0 - 64 + k) << 10) + pidx] = s[k];
        } else {
            #pragma unroll
            for (int k = 0; k < 4; ++k)
                Cv[((size_t)(b * 16 + o0 - 80 + k) << 10) + pidx] = s[k];
        }
    }
}

// ---------------------------------------------------------------------------
// Main fused kernel (round-0 proven version): 4096 blocks = (b, v, d,
// n-chunk of 8). Stages 8 planes of s_prev into LDS with row stride 34
// (bank delta never 0 for any of the 8 rotations) + zero guard border, ONE
// sync, then bilinear transport + state update; s_new streamed out
// coalesced; y n-partials via atomicAdd (y pre-zeroed by hipMemsetAsync).
// Short block lifetime + 4 blocks/CU is what keeps this latency-tolerant;
// the 2048-block merged variant spilled its register prefetch and ran 2.3x
// slower (round-1 post-mortem).
// Plane layout: idx = n*1156 + (y+1)*34 + (x+1), y,x in -1..32.
// ---------------------------------------------------------------------------
__global__ __launch_bounds__(256) void fused_state_kernel(
    const float* __restrict__ s_prev, const float* __restrict__ u_t,
    const float* __restrict__ delta, const float* __restrict__ Bv,
    const float* __restrict__ Cv, const float* __restrict__ logA,
    const float* __restrict__ Dp, float* __restrict__ y_out,
    float* __restrict__ s_out)
{
    __shared__ float lds[8 * 1156];   // 36992 B
    __shared__ float Ash[8];
    int blk = blockIdx.x;
    int cchunk = blk & 1;
    int d = (blk >> 1) & 63, v = (blk >> 7) & 7, b = blk >> 10;
    int t = threadIdx.x;

    if (t < 8) Ash[t] = -__expf(logA[d * 16 + cchunk * 8 + t]);
    // zero guard cells (8 planes x 132)
    for (int k = t; k < 1056; k += 256) {
        int pl = k / 132, g = k - pl * 132;
        int idx;
        if (g < 34)       idx = g;                  // row 0
        else if (g < 68)  idx = 1122 + (g - 34);    // row 33
        else if (g < 100) idx = (g - 67) * 34;      // col 0, rows 1..32
        else              idx = (g - 99) * 34 + 33; // col 33, rows 1..32
        lds[pl * 1156 + idx] = 0.f;
    }

    size_t so = (((size_t)((b * 8 + v) * 64 + d)) << 14) + (cchunk << 13);
    const float4* src = (const float4*)(s_prev + so);
    #pragma unroll
    for (int k = 0; k < 8; ++k) {
        int q = t + (k << 8);
        float4 val = src[q];
        int lin = q << 2;
        int nn = lin >> 10, rem = lin & 1023;
        int di = nn * 1156 + ((rem >> 5) + 1) * 34 + (rem & 31) + 1;
        lds[di] = val.x; lds[di + 1] = val.y; lds[di + 2] = val.z; lds[di + 3] = val.w;
    }
    __syncthreads();

    const float cc = CTAB[v], ss = STAB[v];
    const float* dpl = delta + ((size_t)(b * 64 + d) << 10);
    const float* upl = u_t   + ((size_t)(b * 64 + d) << 10);
    const float* bvc = Bv + ((size_t)b << 14) + (cchunk << 13);
    const float* cvc = Cv + ((size_t)b << 14) + (cchunk << 13);
    float* soc = s_out + so;
    float* yo  = y_out + (((size_t)((b * 8 + v) * 64 + d)) << 10);
    float Dd = Dp[d];

    for (int i = 0; i < 4; ++i) {
        int p = t + (i << 8);
        int h = p >> 5, wpx = p & 31;
        float X = (wpx + 0.5f) * 0.0625f - 1.f;
        float Y = (h + 0.5f) * 0.0625f - 1.f;
        float gx = cc * X - ss * Y;
        float gy = ss * X + cc * Y;
        float ix = (gx + 1.f) * 16.f - 0.5f;
        float iy = (gy + 1.f) * 16.f - 0.5f;
        float fx0 = floorf(ix), fy0 = floorf(iy);
        float wx = ix - fx0, wy = iy - fy0;
        int x0 = (int)fx0, y0 = (int)fy0;
        float mx0 = (x0 >= 0 && x0 < 32) ? (1.f - wx) : 0.f;
        float mx1 = (x0 >= -1 && x0 < 31) ? wx : 0.f;
        float my0 = (y0 >= 0 && y0 < 32) ? (1.f - wy) : 0.f;
        float my1 = (y0 >= -1 && y0 < 31) ? wy : 0.f;
        float w00 = my0 * mx0, w01 = my0 * mx1;
        float w10 = my1 * mx0, w11 = my1 * mx1;
        int bx = min(max(x0, -1), 31), by = min(max(y0, -1), 31);
        int base = (by + 1) * 34 + (bx + 1);   // taps: +0,+1,+34,+35 (guard is zeroed)

        float dd = dpl[p], uv = upl[p];
        float du = dd * uv;
        float yacc = 0.f;
        #pragma unroll
        for (int nn = 0; nn < 8; ++nn) {
            int si = base + nn * 1156;
            float s00 = lds[si], s01 = lds[si + 1];
            float s10 = lds[si + 34], s11 = lds[si + 35];
            float bil = s00 * w00 + s01 * w01 + s10 * w10 + s11 * w11;
            float abar = __expf(dd * Ash[nn]);
            float bvv = bvc[(nn << 10) + p];
            float sn = abar * bil + du * bvv;
            soc[(nn << 10) + p] = sn;
            yacc += sn * cvc[(nn << 10) + p];
        }
        float val = yacc + (cchunk == 0 ? uv * Dd : 0.f);
        atomicAdd(yo + p, val);
    }
}

// ---------------------------------------------------------------------------
extern "C" void kernel_launch(void* const* d_in, const int* in_sizes, int n_in,
                              void* d_out, int out_size, void* d_ws, size_t ws_size,
                              hipStream_t stream)
{
    const float* u_t    = (const float*)d_in[0];
    const float* s_prev = (const float*)d_in[1];
    const float* gn_w   = (const float*)d_in[2];
    const float* gn_b   = (const float*)d_in[3];
    const float* wd     = (const float*)d_in[4];
    const float* bd     = (const float*)d_in[5];
    const float* wB     = (const float*)d_in[6];
    const float* wC     = (const float*)d_in[7];
    const float* logA   = (const float*)d_in[8];
    const float* Dp     = (const float*)d_in[9];
    const float* dtb    = (const float*)d_in[10];

    float* y_out = (float*)d_out;            // (4,8,64,32,32) = 2097152 floats
    float* s_out = y_out + 2097152;          // (4,8,64,16,32,32) = 33554432 floats

    float* up    = (float*)d_ws;             // padded u_norm: 4*64*1156 = 295936
    float* delta = up + 295936;              // 4*64*1024 = 262144
    float* Bv    = delta + 262144;           // 4*16*1024 = 65536
    float* Cv    = Bv + 65536;               // 65536

    // y is accumulated via atomicAdd from the two n-chunk blocks -> zero first
    hipMemsetAsync(y_out, 0, (size_t)2097152 * sizeof(float), stream);

    hipLaunchKernelGGL(gn_kernel, dim3(16), dim3(1024), 0, stream, u_t, gn_w, gn_b, up);
    hipLaunchKernelGGL(conv_kernel, dim3(768), dim3(256), 0, stream,
                       up, wd, bd, wB, wC, dtb, delta, Bv, Cv);
    hipLaunchKernelGGL(fused_state_kernel, dim3(4096), dim3(256), 0, stream,
                       s_prev, u_t, delta, Bv, Cv, logA, Dp, y_out, s_out);
}

// Round 3
// 303.071 us; speedup vs baseline: 1.3559x; 1.0073x over previous
//
#include <hip/hip_runtime.h>
#include <cmath>

// Shapes: B=4, V=8, D=64, N=16, H=32, W=32, GROUPS=4
// rotation tables: a = radians(-45*v); c = cos(a), s = sin(a)
#define FSQ 0.70710678118654752440f
__constant__ float CTAB[8] = {1.f,  FSQ, 0.f, -FSQ, -1.f, -FSQ, 0.f, FSQ};
__constant__ float STAB[8] = {0.f, -FSQ, -1.f, -FSQ,  0.f,  FSQ, 1.f, FSQ};

// ---------------------------------------------------------------------------
// GroupNorm: 16 blocks = (b, group), 1024 threads. Wave-shuffle reduction.
// Writes u_norm into zero-padded (34x34) planes in ws.
// ---------------------------------------------------------------------------
__global__ __launch_bounds__(1024) void gn_kernel(const float* __restrict__ u,
                                                  const float* __restrict__ gw,
                                                  const float* __restrict__ gb,
                                                  float* __restrict__ up)
{
    int blk = blockIdx.x;            // b*4 + g
    int b = blk >> 2, g = blk & 3;
    int t = threadIdx.x;
    const float* src = u + ((size_t)(b * 64 + g * 16) << 10);   // 16384 floats
    float sum = 0.f, sq = 0.f;
    #pragma unroll
    for (int r = 0; r < 16; ++r) {
        float v = src[t + (r << 10)];
        sum += v; sq += v * v;
    }
    // wave-level reduce (64 lanes)
    #pragma unroll
    for (int ofs = 32; ofs > 0; ofs >>= 1) {
        sum += __shfl_down(sum, ofs);
        sq  += __shfl_down(sq, ofs);
    }
    __shared__ float red[16], red2[16];
    int wv = t >> 6;
    if ((t & 63) == 0) { red[wv] = sum; red2[wv] = sq; }
    __syncthreads();
    float s_tot = 0.f, q_tot = 0.f;
    #pragma unroll
    for (int k = 0; k < 16; ++k) { s_tot += red[k]; q_tot += red2[k]; }
    float mu  = s_tot * (1.f / 16384.f);
    float var = q_tot * (1.f / 16384.f) - mu * mu;
    float rs  = rsqrtf(var + 1e-5f);

    float* pb = up + (size_t)(b * 64 + g * 16) * 1156;
    // zero the 132 border cells of each of my 16 padded planes
    for (int k = t; k < 16 * 132; k += 1024) {
        int pl = k / 132, c = k - pl * 132;
        int idx;
        if (c < 34)       idx = c;                       // row 0
        else if (c < 68)  idx = 33 * 34 + (c - 34);      // row 33
        else if (c < 100) idx = (c - 68 + 1) * 34;       // col 0, rows 1..32
        else              idx = (c - 100 + 1) * 34 + 33; // col 33, rows 1..32
        pb[pl * 1156 + idx] = 0.f;
    }
    // normalized data cells: idx = r*1024 + t -> ch = r, pixel = t
    int y = t >> 5, x = t & 31;
    #pragma unroll
    for (int r = 0; r < 16; ++r) {
        float val = (src[t + (r << 10)] - mu) * rs * gw[g * 16 + r] + gb[g * 16 + r];
        pb[r * 1156 + (y + 1) * 34 + (x + 1)] = val;
    }
}

// ---------------------------------------------------------------------------
// 3x3 SAME convs, LDS-staged, 4 OUTPUT CHANNELS PER BLOCK: 768 blocks =
// (b, ogroup, strip). Each block stages the 6-row x 34-col x 64-ci input
// strip (52 KB) into LDS once, then each LDS tap read is FMA'd into 4
// accumulators (one per output channel). ogroups align with weight arrays:
// og 0..15 -> conv_delta, 16..19 -> conv_B, 20..23 -> conv_C.
// ---------------------------------------------------------------------------
__global__ __launch_bounds__(256) void conv_kernel(const float* __restrict__ up,
                                                   const float* __restrict__ wd,
                                                   const float* __restrict__ bd,
                                                   const float* __restrict__ wB,
                                                   const float* __restrict__ wC,
                                                   const float* __restrict__ dtb,
                                                   float* __restrict__ delta,
                                                   float* __restrict__ Bv,
                                                   float* __restrict__ Cv)
{
    __shared__ float sin_[64 * 204];   // 64 ci x 6 rows x 34 cols = 52224 B
    int blk = blockIdx.x;              // b*192 + og*8 + strip
    int strip = blk & 7;
    int og = (blk >> 3) % 24;
    int b = blk / 192;
    int h0 = strip * 4;                // output rows h0..h0+3; padded rows h0..h0+5
    int t = threadIdx.x;

    const float* plane = up + (size_t)b * 73984;   // 64*1156
    for (int idx = t; idx < 13056; idx += 256) {   // 13056 = 64*204 = 256*51
        int ci = idx / 204;
        int rem = idx - ci * 204;
        sin_[idx] = plane[ci * 1156 + h0 * 34 + rem];
    }
    __syncthreads();

    int o0 = og * 4;
    const float* wsel;
    if (o0 < 64)      wsel = wd + (size_t)o0 * 576;
    else if (o0 < 80) wsel = wB + (size_t)(o0 - 64) * 576;
    else              wsel = wC + (size_t)(o0 - 80) * 576;

    int half = t >> 7;                 // ci-half (wave-uniform)
    int px = t & 127;
    int r = px >> 5, c = px & 31;      // output row-in-strip, col
    const float* base = sin_ + r * 34 + c;

    float acc0 = 0.f, acc1 = 0.f, acc2 = 0.f, acc3 = 0.f;
    int ci0 = half * 32;
    for (int ci = ci0; ci < ci0 + 32; ++ci) {
        const float* pp = base + ci * 204;
        const float* wp = wsel + ci * 9;
        #pragma unroll
        for (int dy = 0; dy < 3; ++dy)
            #pragma unroll
            for (int dx = 0; dx < 3; ++dx) {
                float v = pp[dy * 34 + dx];
                int wi = dy * 3 + dx;
                acc0 += v * wp[wi];
                acc1 += v * wp[576 + wi];
                acc2 += v * wp[1152 + wi];
                acc3 += v * wp[1728 + wi];
            }
    }
    __syncthreads();                   // sin_ reuse as reduction scratch
    float4* red4 = (float4*)sin_;
    red4[t] = make_float4(acc0, acc1, acc2, acc3);
    __syncthreads();
    if (t < 128) {
        float4 a = red4[t], bq = red4[t + 128];
        float s0 = a.x + bq.x, s1 = a.y + bq.y, s2 = a.z + bq.z, s3 = a.w + bq.w;
        float s[4] = {s0, s1, s2, s3};
        int pidx = (h0 + r) * 32 + c;  // for t<128: r,c as computed above
        if (o0 < 64) {
            #pragma unroll
            for (int k = 0; k < 4; ++k) {
                float x = s[k] + bd[o0 + k] + dtb[0];
                float sp = (x > 20.f) ? x : log1pf(expf(x));
                sp = fminf(fmaxf(sp, 1e-4f), 5.f);
                delta[((size_t)(b * 64 + o0 + k) << 10) + pidx] = sp;
            }
        } else if (o0 < 80) {
            #pragma unroll
            for (int k = 0; k < 4; ++k)
                Bv[((size_t)(b * 16 + o0 - 64 + k) << 10) + pidx] = s[k];
        } else {
            #pragma unroll
            for (int k = 0; k < 4; ++k)
                Cv[((size_t)(b * 16 + o0 - 80 + k) << 10) + pidx] = s[k];
        }
    }
}

// ---------------------------------------------------------------------------
// Main fused kernel: 8192 blocks = (b, v, d, n-chunk of 4). 4 planes of
// s_prev staged in LDS (19 KB -> 8 blocks/CU = 32 waves, 2x the occupancy
// of the 8-plane version whose 37 KB LDS capped residency at 4 blocks/CU;
// that version measured 86 us at 35% occupancy / 2.57 TB/s — latency-bound).
// Row stride 35 (odd, =3 mod 32): column-order reads of the 90-degree
// rotations walk all 32 banks (stride-34 had bank step 2 -> 4-way), and
// staging-write lane groups pair only 2-way (free).
// Round-1 lesson: NO register state held across phases (spill -> 2.3x).
// Plane layout: idx = n*1190 + (y+1)*35 + (x+1), y,x in -1..32; pad col 34
// never read (taps reach col<=33), so only the 132 border cells are zeroed.
// y n-partials via atomicAdd (4 per pixel, resolve in L2); y pre-zeroed.
// ---------------------------------------------------------------------------
__global__ __launch_bounds__(256) void fused_state_kernel(
    const float* __restrict__ s_prev, const float* __restrict__ u_t,
    const float* __restrict__ delta, const float* __restrict__ Bv,
    const float* __restrict__ Cv, const float* __restrict__ logA,
    const float* __restrict__ Dp, float* __restrict__ y_out,
    float* __restrict__ s_out)
{
    __shared__ float lds[4 * 1190];   // 19040 B
    __shared__ float Ash[4];
    int blk = blockIdx.x;             // b*2048 + v*256 + d*4 + cchunk
    int cchunk = blk & 3;
    int d = (blk >> 2) & 63, v = (blk >> 8) & 7, b = blk >> 11;
    int t = threadIdx.x;

    if (t < 4) Ash[t] = -__expf(logA[d * 16 + cchunk * 4 + t]);
    // zero guard cells (4 planes x 132 border cells; pad col 34 never read)
    for (int k = t; k < 528; k += 256) {
        int pl = k / 132, g = k - pl * 132;
        int idx;
        if (g < 34)       idx = g;                   // row 0
        else if (g < 68)  idx = 33 * 35 + (g - 34);  // row 33
        else if (g < 100) idx = (g - 67) * 35;       // col 0, rows 1..32
        else              idx = (g - 99) * 35 + 33;  // col 33, rows 1..32
        lds[pl * 1190 + idx] = 0.f;
    }

    // 4 planes = 4096 floats per (b,v,d,chunk)
    size_t so = (((size_t)((b * 8 + v) * 64 + d)) << 14) + ((size_t)cchunk << 12);
    const float4* src = (const float4*)(s_prev + so);
    #pragma unroll
    for (int k = 0; k < 4; ++k) {
        int q = t + (k << 8);          // 0..1023 float4s
        float4 val = src[q];
        int lin = q << 2;              // 0..4095
        int nn = lin >> 10, rem = lin & 1023;
        int di = nn * 1190 + ((rem >> 5) + 1) * 35 + (rem & 31) + 1;
        lds[di] = val.x; lds[di + 1] = val.y; lds[di + 2] = val.z; lds[di + 3] = val.w;
    }
    __syncthreads();

    const float cc = CTAB[v], ss = STAB[v];
    const float* dpl = delta + ((size_t)(b * 64 + d) << 10);
    const float* upl = u_t   + ((size_t)(b * 64 + d) << 10);
    const float* bvc = Bv + ((size_t)b << 14) + (cchunk << 12);
    const float* cvc = Cv + ((size_t)b << 14) + (cchunk << 12);
    float* soc = s_out + so;
    float* yo  = y_out + (((size_t)((b * 8 + v) * 64 + d)) << 10);
    float Dd = Dp[d];

    for (int i = 0; i < 4; ++i) {
        int p = t + (i << 8);
        int h = p >> 5, wpx = p & 31;
        float X = (wpx + 0.5f) * 0.0625f - 1.f;
        float Y = (h + 0.5f) * 0.0625f - 1.f;
        float gx = cc * X - ss * Y;
        float gy = ss * X + cc * Y;
        float ix = (gx + 1.f) * 16.f - 0.5f;
        float iy = (gy + 1.f) * 16.f - 0.5f;
        float fx0 = floorf(ix), fy0 = floorf(iy);
        float wx = ix - fx0, wy = iy - fy0;
        int x0 = (int)fx0, y0 = (int)fy0;
        float mx0 = (x0 >= 0 && x0 < 32) ? (1.f - wx) : 0.f;
        float mx1 = (x0 >= -1 && x0 < 31) ? wx : 0.f;
        float my0 = (y0 >= 0 && y0 < 32) ? (1.f - wy) : 0.f;
        float my1 = (y0 >= -1 && y0 < 31) ? wy : 0.f;
        float w00 = my0 * mx0, w01 = my0 * mx1;
        float w10 = my1 * mx0, w11 = my1 * mx1;
        int bx = min(max(x0, -1), 31), by = min(max(y0, -1), 31);
        int base = (by + 1) * 35 + (bx + 1);   // taps: +0,+1,+35,+36 (guard zeroed)

        float dd = dpl[p], uv = upl[p];
        float du = dd * uv;
        float yacc = 0.f;
        #pragma unroll
        for (int nn = 0; nn < 4; ++nn) {
            int si = base + nn * 1190;
            float s00 = lds[si], s01 = lds[si + 1];
            float s10 = lds[si + 35], s11 = lds[si + 36];
            float bil = s00 * w00 + s01 * w01 + s10 * w10 + s11 * w11;
            float abar = __expf(dd * Ash[nn]);
            float bvv = bvc[(nn << 10) + p];
            float sn = abar * bil + du * bvv;
            soc[(nn << 10) + p] = sn;
            yacc += sn * cvc[(nn << 10) + p];
        }
        float val = yacc + (cchunk == 0 ? uv * Dd : 0.f);
        atomicAdd(yo + p, val);
    }
}

// ---------------------------------------------------------------------------
extern "C" void kernel_launch(void* const* d_in, const int* in_sizes, int n_in,
                              void* d_out, int out_size, void* d_ws, size_t ws_size,
                              hipStream_t stream)
{
    const float* u_t    = (const float*)d_in[0];
    const float* s_prev = (const float*)d_in[1];
    const float* gn_w   = (const float*)d_in[2];
    const float* gn_b   = (const float*)d_in[3];
    const float* wd     = (const float*)d_in[4];
    const float* bd     = (const float*)d_in[5];
    const float* wB     = (const float*)d_in[6];
    const float* wC     = (const float*)d_in[7];
    const float* logA   = (const float*)d_in[8];
    const float* Dp     = (const float*)d_in[9];
    const float* dtb    = (const float*)d_in[10];

    float* y_out = (float*)d_out;            // (4,8,64,32,32) = 2097152 floats
    float* s_out = y_out + 2097152;          // (4,8,64,16,32,32) = 33554432 floats

    float* up    = (float*)d_ws;             // padded u_norm: 4*64*1156 = 295936
    float* delta = up + 295936;              // 4*64*1024 = 262144
    float* Bv    = delta + 262144;           // 4*16*1024 = 65536
    float* Cv    = Bv + 65536;               // 65536

    // y is accumulated via atomicAdd from the four n-chunk blocks -> zero first
    hipMemsetAsync(y_out, 0, (size_t)2097152 * sizeof(float), stream);

    hipLaunchKernelGGL(gn_kernel, dim3(16), dim3(1024), 0, stream, u_t, gn_w, gn_b, up);
    hipLaunchKernelGGL(conv_kernel, dim3(768), dim3(256), 0, stream,
                       up, wd, bd, wB, wC, dtb, delta, Bv, Cv);
    hipLaunchKernelGGL(fused_state_kernel, dim3(8192), dim3(256), 0, stream,
                       s_prev, u_t, delta, Bv, Cv, logA, Dp, y_out, s_out);
}